// Round 3
// baseline (9314.864 us; speedup 1.0000x reference)
//
#include <hip/hip_runtime.h>

#define NL    5
#define NN    100000
#define NE    200000
#define MPAD  100096       // 782 * 128
#define MTILES 782
#define K1    320          // EMB 300 padded
#define N1    640          // 600 padded
#define K2    640
#define N2    384          // 300 padded
#define BN_EPS 1e-5f

typedef __attribute__((ext_vector_type(8))) short   short8;
typedef __attribute__((ext_vector_type(4))) float   floatx4;

// exact hi/lo bf16 split: x == bf(hi) + bf(lo) + O(2^-17 |x|)
__device__ inline void splitbf(float x, unsigned short& hi, unsigned short& lo) {
    unsigned u = __float_as_uint(x);
    unsigned hb = u & 0xFFFF0000u;
    float lf = x - __uint_as_float(hb);     // exact (shares leading bits)
    hi = (unsigned short)(u >> 16);
    lo = (unsigned short)(__float_as_uint(lf) >> 16);
}
__device__ inline unsigned short f2bf(float f) {
    unsigned u = __float_as_uint(f);
    unsigned r = u + 0x7FFFu + ((u >> 16) & 1u);   // RNE
    return (unsigned short)(r >> 16);
}
__device__ inline float bf2f(unsigned short b) {
    return __uint_as_float(((unsigned)b) << 16);
}

// ---------------- weight prep: hi/lo planes, n-major, padded ----------------
__global__ void prep_w1(const float* __restrict__ W1,
                        unsigned short* __restrict__ Whi, unsigned short* __restrict__ Wlo) {
    int idx = blockIdx.x * blockDim.x + threadIdx.x;
    if (idx >= NL * N1 * K1) return;                // [l][n<640][k<320]
    int l = idx / (N1 * K1);
    int rem = idx % (N1 * K1);
    int n = rem / K1;
    int k = rem % K1;
    float v = (k < 300 && n < 600) ? W1[((long)l * 300 + k) * 600 + n] : 0.f;
    unsigned short hi, lo; splitbf(v, hi, lo);
    Whi[idx] = hi; Wlo[idx] = lo;
}

__global__ void prep_w2(const float* __restrict__ W2,
                        unsigned short* __restrict__ Whi, unsigned short* __restrict__ Wlo) {
    int idx = blockIdx.x * blockDim.x + threadIdx.x;
    if (idx >= NL * N2 * K2) return;                // [l][d<384][k<640]
    int l = idx / (N2 * K2);
    int rem = idx % (N2 * K2);
    int d = rem / K2;
    int k = rem % K2;
    float v = (d < 300 && k < 600) ? W2[((long)l * 600 + k) * 300 + d] : 0.f;
    unsigned short hi, lo; splitbf(v, hi, lo);
    Whi[idx] = hi; Wlo[idx] = lo;
}

__global__ void prep_vec(const float* __restrict__ b1, const float* __restrict__ g1, const float* __restrict__ be1,
                         const float* __restrict__ b2, const float* __restrict__ g2, const float* __restrict__ be2,
                         float* __restrict__ b1p, float* __restrict__ g1p, float* __restrict__ be1p,
                         float* __restrict__ b2p, float* __restrict__ g2p, float* __restrict__ be2p) {
    int idx = blockIdx.x * blockDim.x + threadIdx.x;
    if (idx < NL * N1) {
        int l = idx / N1, n = idx % N1;
        bool ok = (n < 600);
        b1p[idx]  = ok ? b1[l * 600 + n]  : 0.f;
        g1p[idx]  = ok ? g1[l * 600 + n]  : 0.f;
        be1p[idx] = ok ? be1[l * 600 + n] : 0.f;
    }
    if (idx < NL * N2) {
        int l = idx / N2, d = idx % N2;
        bool ok = (d < 300);
        b2p[idx]  = ok ? b2[l * 300 + d]  : 0.f;
        g2p[idx]  = ok ? g2[l * 300 + d]  : 0.f;
        be2p[idx] = ok ? be2[l * 300 + d] : 0.f;
    }
}

// ---------------- atom encoder ----------------
__global__ void atom_enc(const int* __restrict__ xf, const float* __restrict__ tab,
                         float* __restrict__ h) {
    int idx = blockIdx.x * blockDim.x + threadIdx.x;
    if (idx >= NN * 75) return;
    int n = idx / 75;
    int c = (idx % 75) * 4;
    float4 s = make_float4(0.f, 0.f, 0.f, 0.f);
#pragma unroll
    for (int f = 0; f < 9; f++) {
        int v = xf[n * 9 + f];
        const float4 t = *(const float4*)(tab + (long)(f * 119 + v) * 300 + c);
        s.x += t.x; s.y += t.y; s.z += t.z; s.w += t.w;
    }
    *(float4*)(h + (long)n * 300 + c) = s;
}

// ---------------- edge scatter: agg[dst] += relu(h[src] + bond_sum) ----------------
__global__ void scatter_msg(const float* __restrict__ h, const int* __restrict__ ei,
                            const int* __restrict__ ea, const float* __restrict__ bond,
                            float* __restrict__ agg) {
    int idx = blockIdx.x * blockDim.x + threadIdx.x;
    if (idx >= NE * 75) return;
    int e = idx / 75;
    int c = (idx % 75) * 4;
    int src = ei[e];
    int dst = ei[NE + e];
    int a0 = ea[e * 3 + 0], a1 = ea[e * 3 + 1], a2 = ea[e * 3 + 2];
    const float4 hv = *(const float4*)(h + (long)src * 300 + c);
    const float4 t0 = *(const float4*)(bond + (0 * 6 + a0) * 300 + c);
    const float4 t1 = *(const float4*)(bond + (1 * 6 + a1) * 300 + c);
    const float4 t2 = *(const float4*)(bond + (2 * 6 + a2) * 300 + c);
    float* ap = agg + (long)dst * 300 + c;
    float m;
    m = hv.x + t0.x + t1.x + t2.x; atomicAdd(ap + 0, m > 0.f ? m : 0.f);
    m = hv.y + t0.y + t1.y + t2.y; atomicAdd(ap + 1, m > 0.f ? m : 0.f);
    m = hv.z + t0.z + t1.z + t2.z; atomicAdd(ap + 2, m > 0.f ? m : 0.f);
    m = hv.w + t0.w + t1.w + t2.w; atomicAdd(ap + 3, m > 0.f ? m : 0.f);
}

// ---------------- GEMM1 fused: z1 = [(1+eps)h + agg] @ W1 + b1 ----------------
// A staged on the fly (f32 -> exact hi/lo split in VGPRs -> LDS); B = pre-split
// planes via global_load_lds. 3 MFMAs per frag pair: hi*hi + lo*hi + hi*lo.
// Epilogue: exact f32 stats (rows<NN), z1 stored bf16 (the ONLY rounding source).
__global__ __launch_bounds__(256, 2)
void gemm1_fused(const float* __restrict__ h, const float* __restrict__ agg,
                 const float* __restrict__ eps, int l,
                 const unsigned short* __restrict__ Whi, const unsigned short* __restrict__ Wlo,
                 const float* __restrict__ bias, unsigned short* __restrict__ z1b,
                 float* __restrict__ stat_sum, float* __restrict__ stat_sq) {
    __shared__ unsigned short Ah[128 * 32], Al[128 * 32];
    __shared__ unsigned short Bh[128 * 32], Bl[128 * 32];
    __shared__ float ssum[128], ssq[128];

    const int tid  = threadIdx.x;
    const int wave = tid >> 6;
    const int lane = tid & 63;
    const long row0 = (long)blockIdx.y * 128;
    const long col0 = (long)blockIdx.x * 128;

    floatx4 acc[4][4];
#pragma unroll
    for (int mi = 0; mi < 4; mi++)
#pragma unroll
        for (int ni = 0; ni < 4; ni++)
            acc[mi][ni] = (floatx4){0.f, 0.f, 0.f, 0.f};

    const int sr  = lane >> 2;
    const int scb = (lane & 3) * 8;
    const int wm  = (wave >> 1) * 64;
    const int wn  = (wave & 1) * 64;
    const int fr  = lane & 15;
    const int q   = lane >> 4;
    const int arow = tid >> 1;            // A staging: 2 threads/row, 16 cols each
    const int acb  = (tid & 1) * 16;
    const long grow = row0 + arow;
    const bool rok  = grow < NN;
    const float ep = 1.f + eps[l];

    for (int k0 = 0; k0 < K1; k0 += 32) {
#pragma unroll
        for (int i = 0; i < 2; i++) {
            int r = wave * 32 + i * 16;
            const unsigned short* gbh = Whi + (col0 + r + sr) * (long)K1 + k0 + scb;
            const unsigned short* gbl = Wlo + (col0 + r + sr) * (long)K1 + k0 + scb;
            __builtin_amdgcn_global_load_lds((const __attribute__((address_space(1))) void*)gbh,
                                             (__attribute__((address_space(3))) void*)(Bh + r * 32), 16, 0, 0);
            __builtin_amdgcn_global_load_lds((const __attribute__((address_space(1))) void*)gbl,
                                             (__attribute__((address_space(3))) void*)(Bl + r * 32), 16, 0, 0);
        }
#pragma unroll
        for (int j = 0; j < 4; j++) {
            int cc = k0 + acb + j * 4;
            float4 hv, av;
            if (rok && cc < 300) {
                hv = *(const float4*)(h   + grow * 300 + cc);
                av = *(const float4*)(agg + grow * 300 + cc);
            } else {
                hv = make_float4(0.f, 0.f, 0.f, 0.f);
                av = hv;
            }
            ushort4 hi4, lo4;
            splitbf(ep * hv.x + av.x, hi4.x, lo4.x);
            splitbf(ep * hv.y + av.y, hi4.y, lo4.y);
            splitbf(ep * hv.z + av.z, hi4.z, lo4.z);
            splitbf(ep * hv.w + av.w, hi4.w, lo4.w);
            *(ushort4*)(Ah + arow * 32 + acb + j * 4) = hi4;
            *(ushort4*)(Al + arow * 32 + acb + j * 4) = lo4;
        }
        __syncthreads();
        short8 ah[4], alo[4], bh[4], blo[4];
#pragma unroll
        for (int mi = 0; mi < 4; mi++) {
            ah[mi]  = *(const short8*)(Ah + (wm + mi * 16 + fr) * 32 + q * 8);
            alo[mi] = *(const short8*)(Al + (wm + mi * 16 + fr) * 32 + q * 8);
        }
#pragma unroll
        for (int ni = 0; ni < 4; ni++) {
            bh[ni]  = *(const short8*)(Bh + (wn + ni * 16 + fr) * 32 + q * 8);
            blo[ni] = *(const short8*)(Bl + (wn + ni * 16 + fr) * 32 + q * 8);
        }
#pragma unroll
        for (int mi = 0; mi < 4; mi++)
#pragma unroll
            for (int ni = 0; ni < 4; ni++) {
                acc[mi][ni] = __builtin_amdgcn_mfma_f32_16x16x32_bf16(ah[mi],  bh[ni],  acc[mi][ni], 0, 0, 0);
                acc[mi][ni] = __builtin_amdgcn_mfma_f32_16x16x32_bf16(alo[mi], bh[ni],  acc[mi][ni], 0, 0, 0);
                acc[mi][ni] = __builtin_amdgcn_mfma_f32_16x16x32_bf16(ah[mi],  blo[ni], acc[mi][ni], 0, 0, 0);
            }
        __syncthreads();
    }

    if (tid < 128) { ssum[tid] = 0.f; ssq[tid] = 0.f; }
    __syncthreads();
#pragma unroll
    for (int ni = 0; ni < 4; ni++) {
        int cl = wn + ni * 16 + fr;
        long cg = col0 + cl;
        float bs = bias[cg];
        float psum = 0.f, psq = 0.f;
#pragma unroll
        for (int mi = 0; mi < 4; mi++) {
#pragma unroll
            for (int r = 0; r < 4; r++) {
                long rg = row0 + wm + mi * 16 + q * 4 + r;
                float v = acc[mi][ni][r] + bs;
                z1b[rg * N1 + cg] = f2bf(v);
                if (rg < NN) { psum += v; psq += v * v; }
            }
        }
        atomicAdd(&ssum[cl], psum);
        atomicAdd(&ssq[cl], psq);
    }
    __syncthreads();
    if (tid < 128) {
        atomicAdd(&stat_sum[col0 + tid], ssum[tid]);
        atomicAdd(&stat_sq[col0 + tid], ssq[tid]);
    }
}

// ---------------- GEMM2 fused: z2 = relu(BN(z1)) @ W2 + b2 ----------------
// A staged from bf16 z1 + per-k scale/shift (LDS-cached) + ReLU + exact split.
__global__ __launch_bounds__(256, 2)
void gemm2_fused(const unsigned short* __restrict__ z1b,
                 const float* __restrict__ scale, const float* __restrict__ shift,
                 const unsigned short* __restrict__ Whi, const unsigned short* __restrict__ Wlo,
                 const float* __restrict__ bias, float* __restrict__ z2f,
                 float* __restrict__ stat_sum, float* __restrict__ stat_sq) {
    __shared__ unsigned short Ah[128 * 32], Al[128 * 32];
    __shared__ unsigned short Bh[128 * 32], Bl[128 * 32];
    __shared__ float sSc[K2], sSh[K2];
    __shared__ float ssum[128], ssq[128];

    const int tid  = threadIdx.x;
    const int wave = tid >> 6;
    const int lane = tid & 63;
    const long row0 = (long)blockIdx.y * 128;
    const long col0 = (long)blockIdx.x * 128;

    for (int i = tid; i < K2; i += 256) { sSc[i] = scale[i]; sSh[i] = shift[i]; }

    floatx4 acc[4][4];
#pragma unroll
    for (int mi = 0; mi < 4; mi++)
#pragma unroll
        for (int ni = 0; ni < 4; ni++)
            acc[mi][ni] = (floatx4){0.f, 0.f, 0.f, 0.f};

    const int sr  = lane >> 2;
    const int scb = (lane & 3) * 8;
    const int wm  = (wave >> 1) * 64;
    const int wn  = (wave & 1) * 64;
    const int fr  = lane & 15;
    const int q   = lane >> 4;
    const int arow = tid >> 1;
    const int acb  = (tid & 1) * 16;
    const long grow = row0 + arow;
    const bool rok  = grow < NN;
    __syncthreads();     // sSc/sSh visible

    for (int k0 = 0; k0 < K2; k0 += 32) {
#pragma unroll
        for (int i = 0; i < 2; i++) {
            int r = wave * 32 + i * 16;
            const unsigned short* gbh = Whi + (col0 + r + sr) * (long)K2 + k0 + scb;
            const unsigned short* gbl = Wlo + (col0 + r + sr) * (long)K2 + k0 + scb;
            __builtin_amdgcn_global_load_lds((const __attribute__((address_space(1))) void*)gbh,
                                             (__attribute__((address_space(3))) void*)(Bh + r * 32), 16, 0, 0);
            __builtin_amdgcn_global_load_lds((const __attribute__((address_space(1))) void*)gbl,
                                             (__attribute__((address_space(3))) void*)(Bl + r * 32), 16, 0, 0);
        }
#pragma unroll
        for (int j = 0; j < 4; j++) {
            int cc = k0 + acb + j * 4;
            ushort4 xv;
            if (rok) xv = *(const ushort4*)(z1b + grow * K2 + cc);
            else     { xv.x = 0; xv.y = 0; xv.z = 0; xv.w = 0; }
            const float4 sc = *(const float4*)(sSc + cc);
            const float4 sh = *(const float4*)(sSh + cc);
            ushort4 hi4, lo4;
            splitbf(fmaxf(bf2f(xv.x) * sc.x + sh.x, 0.f), hi4.x, lo4.x);
            splitbf(fmaxf(bf2f(xv.y) * sc.y + sh.y, 0.f), hi4.y, lo4.y);
            splitbf(fmaxf(bf2f(xv.z) * sc.z + sh.z, 0.f), hi4.z, lo4.z);
            splitbf(fmaxf(bf2f(xv.w) * sc.w + sh.w, 0.f), hi4.w, lo4.w);
            *(ushort4*)(Ah + arow * 32 + acb + j * 4) = hi4;
            *(ushort4*)(Al + arow * 32 + acb + j * 4) = lo4;
        }
        __syncthreads();
        short8 ah[4], alo[4], bh[4], blo[4];
#pragma unroll
        for (int mi = 0; mi < 4; mi++) {
            ah[mi]  = *(const short8*)(Ah + (wm + mi * 16 + fr) * 32 + q * 8);
            alo[mi] = *(const short8*)(Al + (wm + mi * 16 + fr) * 32 + q * 8);
        }
#pragma unroll
        for (int ni = 0; ni < 4; ni++) {
            bh[ni]  = *(const short8*)(Bh + (wn + ni * 16 + fr) * 32 + q * 8);
            blo[ni] = *(const short8*)(Bl + (wn + ni * 16 + fr) * 32 + q * 8);
        }
#pragma unroll
        for (int mi = 0; mi < 4; mi++)
#pragma unroll
            for (int ni = 0; ni < 4; ni++) {
                acc[mi][ni] = __builtin_amdgcn_mfma_f32_16x16x32_bf16(ah[mi],  bh[ni],  acc[mi][ni], 0, 0, 0);
                acc[mi][ni] = __builtin_amdgcn_mfma_f32_16x16x32_bf16(alo[mi], bh[ni],  acc[mi][ni], 0, 0, 0);
                acc[mi][ni] = __builtin_amdgcn_mfma_f32_16x16x32_bf16(ah[mi],  blo[ni], acc[mi][ni], 0, 0, 0);
            }
        __syncthreads();
    }

    if (tid < 128) { ssum[tid] = 0.f; ssq[tid] = 0.f; }
    __syncthreads();
#pragma unroll
    for (int ni = 0; ni < 4; ni++) {
        int cl = wn + ni * 16 + fr;
        long cg = col0 + cl;
        float bs = bias[cg];
        float psum = 0.f, psq = 0.f;
#pragma unroll
        for (int mi = 0; mi < 4; mi++) {
#pragma unroll
            for (int r = 0; r < 4; r++) {
                long rg = row0 + wm + mi * 16 + q * 4 + r;
                float v = acc[mi][ni][r] + bs;
                if (cg < 300) z2f[rg * 300 + cg] = v;
                if (rg < NN) { psum += v; psq += v * v; }
            }
        }
        atomicAdd(&ssum[cl], psum);
        atomicAdd(&ssq[cl], psq);
    }
    __syncthreads();
    if (tid < 128) {
        atomicAdd(&stat_sum[col0 + tid], ssum[tid]);
        atomicAdd(&stat_sq[col0 + tid], ssq[tid]);
    }
}

// ---------------- BN finalize ----------------
__global__ void bn_finalize(const float* __restrict__ sum, const float* __restrict__ sq,
                            const float* __restrict__ g, const float* __restrict__ be,
                            float* __restrict__ scale, float* __restrict__ shift, int n) {
    int c = blockIdx.x * blockDim.x + threadIdx.x;
    if (c >= n) return;
    const float invN = 1.f / (float)NN;
    float mu  = sum[c] * invN;
    float var = sq[c] * invN - mu * mu;
    float rs  = rsqrtf(var + BN_EPS);
    float s   = rs * g[c];               // pad cols: g=0 -> s=0
    scale[c] = s;
    shift[c] = be[c] - mu * s;
}

// ---------------- final BN (+ReLU except last layer) -> f32 h ----------------
__global__ void bn2_out(const float* __restrict__ z2,
                        const float* __restrict__ scale, const float* __restrict__ shift,
                        float* __restrict__ out, int do_relu) {
    int idx = blockIdx.x * blockDim.x + threadIdx.x;
    if (idx >= NN * 75) return;
    int n = idx / 75;
    int c = (idx % 75) * 4;
    const float4 v  = *(const float4*)(z2 + (long)n * 300 + c);
    const float4 sc = *(const float4*)(scale + c);
    const float4 sh = *(const float4*)(shift + c);
    float4 o;
    o.x = v.x * sc.x + sh.x;
    o.y = v.y * sc.y + sh.y;
    o.z = v.z * sc.z + sh.z;
    o.w = v.w * sc.w + sh.w;
    if (do_relu) {
        o.x = fmaxf(o.x, 0.f); o.y = fmaxf(o.y, 0.f);
        o.z = fmaxf(o.z, 0.f); o.w = fmaxf(o.w, 0.f);
    }
    *(float4*)(out + (long)n * 300 + c) = o;
}

extern "C" void kernel_launch(void* const* d_in, const int* in_sizes, int n_in,
                              void* d_out, int out_size, void* d_ws, size_t ws_size,
                              hipStream_t stream) {
    const int*   xf   = (const int*)d_in[0];
    const int*   ei   = (const int*)d_in[1];
    const int*   ea   = (const int*)d_in[2];
    const float* atab = (const float*)d_in[3];
    const float* btab = (const float*)d_in[4];
    const float* eps  = (const float*)d_in[5];
    const float* W1   = (const float*)d_in[6];
    const float* b1   = (const float*)d_in[7];
    const float* g1   = (const float*)d_in[8];
    const float* be1  = (const float*)d_in[9];
    const float* W2   = (const float*)d_in[10];
    const float* b2   = (const float*)d_in[11];
    const float* g2   = (const float*)d_in[12];
    const float* be2  = (const float*)d_in[13];
    float* hbuf = (float*)d_out;                 // h lives in d_out across layers

    char* ws = (char*)d_ws;
    size_t off = 0;
    auto alloc = [&](size_t bytes) { size_t o = off; off += (bytes + 255) & ~(size_t)255; return o; };
    // z1 bf16 [MPAD,640]  (128.1 MB)
    unsigned short* z1b = (unsigned short*)(ws + alloc((size_t)MPAD * N1 * 2));
    // shared region: agg f32 [NN,300] / z2 f32 [MPAD,300]  (120.1 MB)
    char* regA = ws + alloc((size_t)MPAD * 300 * 4);
    float* agg = (float*)regA;
    float* z2f = (float*)regA;
    unsigned short* W1hi = (unsigned short*)(ws + alloc((size_t)NL * N1 * K1 * 2));  // 2.05 MB
    unsigned short* W1lo = (unsigned short*)(ws + alloc((size_t)NL * N1 * K1 * 2));
    unsigned short* W2hi = (unsigned short*)(ws + alloc((size_t)NL * N2 * K2 * 2));  // 2.46 MB
    unsigned short* W2lo = (unsigned short*)(ws + alloc((size_t)NL * N2 * K2 * 2));
    float* b1p  = (float*)(ws + alloc((size_t)NL * N1 * 4));
    float* g1p  = (float*)(ws + alloc((size_t)NL * N1 * 4));
    float* be1p = (float*)(ws + alloc((size_t)NL * N1 * 4));
    float* b2p  = (float*)(ws + alloc((size_t)NL * N2 * 4));
    float* g2p  = (float*)(ws + alloc((size_t)NL * N2 * 4));
    float* be2p = (float*)(ws + alloc((size_t)NL * N2 * 4));
    float* sums = (float*)(ws + alloc(2048 * 4));    // sum1[640] sq1[640] sum2[384] sq2[384]
    float* scale1 = (float*)(ws + alloc(N1 * 4));
    float* shift1 = (float*)(ws + alloc(N1 * 4));
    float* scale2 = (float*)(ws + alloc(N2 * 4));
    float* shift2 = (float*)(ws + alloc(N2 * 4));
    (void)ws_size; (void)in_sizes; (void)n_in; (void)out_size;
    // total ws: ~257.4 MB (R1's 318 MB ran clean; R2's 526 MB core-dumped)

    prep_w1<<<(NL * N1 * K1 + 255) / 256, 256, 0, stream>>>(W1, W1hi, W1lo);
    prep_w2<<<(NL * N2 * K2 + 255) / 256, 256, 0, stream>>>(W2, W2hi, W2lo);
    prep_vec<<<(NL * N1 + 255) / 256, 256, 0, stream>>>(b1, g1, be1, b2, g2, be2,
                                                        b1p, g1p, be1p, b2p, g2p, be2p);
    atom_enc<<<(NN * 75 + 255) / 256, 256, 0, stream>>>(xf, atab, hbuf);

    for (int l = 0; l < NL; l++) {
        hipMemsetAsync(agg, 0, (size_t)NN * 300 * 4, stream);
        hipMemsetAsync(sums, 0, 2048 * 4, stream);
        scatter_msg<<<(NE * 75 + 255) / 256, 256, 0, stream>>>(hbuf, ei, ea, btab + (size_t)l * 5400, agg);
        gemm1_fused<<<dim3(N1 / 128, MTILES), 256, 0, stream>>>(
            hbuf, agg, eps, l, W1hi + (size_t)l * N1 * K1, W1lo + (size_t)l * N1 * K1,
            b1p + l * N1, z1b, sums + 0, sums + 640);
        bn_finalize<<<(N1 + 255) / 256, 256, 0, stream>>>(sums + 0, sums + 640,
            g1p + l * N1, be1p + l * N1, scale1, shift1, N1);
        gemm2_fused<<<dim3(N2 / 128, MTILES), 256, 0, stream>>>(
            z1b, scale1, shift1, W2hi + (size_t)l * N2 * K2, W2lo + (size_t)l * N2 * K2,
            b2p + l * N2, z2f, sums + 1280, sums + 1664);
        bn_finalize<<<(N2 + 255) / 256, 256, 0, stream>>>(sums + 1280, sums + 1664,
            g2p + l * N2, be2p + l * N2, scale2, shift2, N2);
        bn2_out<<<(NN * 75 + 255) / 256, 256, 0, stream>>>(z2f, scale2, shift2, hbuf, (l < NL - 1) ? 1 : 0);
    }
}

// Round 4
// 5642.711 us; speedup vs baseline: 1.6508x; 1.6508x over previous
//
#include <hip/hip_runtime.h>

#define NL    5
#define NN    100000
#define NE    200000
#define MPAD  100096       // 782 * 128
#define MTILES 782
#define K1    320          // EMB 300 padded
#define N1    640          // 600 padded
#define K2    640
#define N2    384          // 300 padded
#define BN_EPS 1e-5f

typedef __attribute__((ext_vector_type(8))) short   short8;
typedef __attribute__((ext_vector_type(4))) float   floatx4;

// exact hi/lo bf16 split: x == bf(hi) + bf(lo) + O(2^-17 |x|)
__device__ inline void splitbf(float x, unsigned short& hi, unsigned short& lo) {
    unsigned u = __float_as_uint(x);
    unsigned hb = u & 0xFFFF0000u;
    float lf = x - __uint_as_float(hb);     // exact (shares leading bits)
    hi = (unsigned short)(u >> 16);
    lo = (unsigned short)(__float_as_uint(lf) >> 16);
}
__device__ inline unsigned short f2bf(float f) {
    unsigned u = __float_as_uint(f);
    unsigned r = u + 0x7FFFu + ((u >> 16) & 1u);   // RNE
    return (unsigned short)(r >> 16);
}
__device__ inline float bf2f(unsigned short b) {
    return __uint_as_float(((unsigned)b) << 16);
}

// ---------------- weight prep: hi/lo planes, n-major, padded ----------------
__global__ void prep_w1(const float* __restrict__ W1,
                        unsigned short* __restrict__ Whi, unsigned short* __restrict__ Wlo) {
    int idx = blockIdx.x * blockDim.x + threadIdx.x;
    if (idx >= NL * N1 * K1) return;                // [l][n<640][k<320]
    int l = idx / (N1 * K1);
    int rem = idx % (N1 * K1);
    int n = rem / K1;
    int k = rem % K1;
    float v = (k < 300 && n < 600) ? W1[((long)l * 300 + k) * 600 + n] : 0.f;
    unsigned short hi, lo; splitbf(v, hi, lo);
    Whi[idx] = hi; Wlo[idx] = lo;
}

__global__ void prep_w2(const float* __restrict__ W2,
                        unsigned short* __restrict__ Whi, unsigned short* __restrict__ Wlo) {
    int idx = blockIdx.x * blockDim.x + threadIdx.x;
    if (idx >= NL * N2 * K2) return;                // [l][d<384][k<640]
    int l = idx / (N2 * K2);
    int rem = idx % (N2 * K2);
    int d = rem / K2;
    int k = rem % K2;
    float v = (d < 300 && k < 600) ? W2[((long)l * 600 + k) * 300 + d] : 0.f;
    unsigned short hi, lo; splitbf(v, hi, lo);
    Whi[idx] = hi; Wlo[idx] = lo;
}

__global__ void prep_vec(const float* __restrict__ b1, const float* __restrict__ g1, const float* __restrict__ be1,
                         const float* __restrict__ b2, const float* __restrict__ g2, const float* __restrict__ be2,
                         float* __restrict__ b1p, float* __restrict__ g1p, float* __restrict__ be1p,
                         float* __restrict__ b2p, float* __restrict__ g2p, float* __restrict__ be2p) {
    int idx = blockIdx.x * blockDim.x + threadIdx.x;
    if (idx < NL * N1) {
        int l = idx / N1, n = idx % N1;
        bool ok = (n < 600);
        b1p[idx]  = ok ? b1[l * 600 + n]  : 0.f;
        g1p[idx]  = ok ? g1[l * 600 + n]  : 0.f;
        be1p[idx] = ok ? be1[l * 600 + n] : 0.f;
    }
    if (idx < NL * N2) {
        int l = idx / N2, d = idx % N2;
        bool ok = (d < 300);
        b2p[idx]  = ok ? b2[l * 300 + d]  : 0.f;
        g2p[idx]  = ok ? g2[l * 300 + d]  : 0.f;
        be2p[idx] = ok ? be2[l * 300 + d] : 0.f;
    }
}

// ---------------- atom encoder ----------------
__global__ void atom_enc(const int* __restrict__ xf, const float* __restrict__ tab,
                         float* __restrict__ h) {
    int idx = blockIdx.x * blockDim.x + threadIdx.x;
    if (idx >= NN * 75) return;
    int n = idx / 75;
    int c = (idx % 75) * 4;
    float4 s = make_float4(0.f, 0.f, 0.f, 0.f);
#pragma unroll
    for (int f = 0; f < 9; f++) {
        int v = xf[n * 9 + f];
        const float4 t = *(const float4*)(tab + (long)(f * 119 + v) * 300 + c);
        s.x += t.x; s.y += t.y; s.z += t.z; s.w += t.w;
    }
    *(float4*)(h + (long)n * 300 + c) = s;
}

// ---------------- CSR build (once per call; graph static across layers) ----------------
__global__ void count_deg(const int* __restrict__ ei, int* __restrict__ deg) {
    int e = blockIdx.x * blockDim.x + threadIdx.x;
    if (e >= NE) return;
    atomicAdd(&deg[ei[NE + e]], 1);
}

// one-block exclusive scan over deg[0..NN) -> rowptr[0..NN]
__global__ void scan_rowptr(const int* __restrict__ deg, int* __restrict__ rowptr) {
    __shared__ int stot[1024];
    const int tid = threadIdx.x;
    const int CH = (NN + 1023) / 1024;     // 98
    const int base = tid * CH;
    int s = 0;
    for (int i = 0; i < CH; i++) {
        int idx = base + i;
        if (idx < NN) s += deg[idx];
    }
    stot[tid] = s;
    __syncthreads();
    for (int offs = 1; offs < 1024; offs <<= 1) {
        int v = (tid >= offs) ? stot[tid - offs] : 0;
        __syncthreads();
        stot[tid] += v;
        __syncthreads();
    }
    int run = (tid == 0) ? 0 : stot[tid - 1];
    for (int i = 0; i < CH; i++) {
        int idx = base + i;
        if (idx <= NN) rowptr[idx] = run;
        if (idx < NN) run += deg[idx];
    }
}

__global__ void fill_csr(const int* __restrict__ ei, const int* __restrict__ ea,
                         const int* __restrict__ rowptr, int* __restrict__ fillc,
                         int* __restrict__ csr_src, int* __restrict__ csr_att) {
    int e = blockIdx.x * blockDim.x + threadIdx.x;
    if (e >= NE) return;
    int dst = ei[NE + e];
    int pos = atomicAdd(&fillc[dst], 1);
    int slot = rowptr[dst] + pos;
    csr_src[slot] = ei[e];
    csr_att[slot] = ea[e * 3] | (ea[e * 3 + 1] << 3) | (ea[e * 3 + 2] << 6);
}

// ---------------- gather aggregation: agg[n] = sum_{e in(n)} relu(h[src]+bond) ----------------
__global__ void gather_agg(const float* __restrict__ h,
                           const int* __restrict__ rowptr,
                           const int* __restrict__ csr_src, const int* __restrict__ csr_att,
                           const float* __restrict__ bond,
                           float* __restrict__ agg) {
    int idx = blockIdx.x * blockDim.x + threadIdx.x;
    if (idx >= NN * 75) return;
    int n = idx / 75;
    int c = (idx % 75) * 4;
    int p0 = rowptr[n], p1 = rowptr[n + 1];
    float4 s = make_float4(0.f, 0.f, 0.f, 0.f);
    for (int j = p0; j < p1; j++) {
        int src = csr_src[j];
        int att = csr_att[j];
        const float4 hv = *(const float4*)(h + (long)src * 300 + c);
        const float4 t0 = *(const float4*)(bond + (0 * 6 + (att & 7)) * 300 + c);
        const float4 t1 = *(const float4*)(bond + (1 * 6 + ((att >> 3) & 7)) * 300 + c);
        const float4 t2 = *(const float4*)(bond + (2 * 6 + ((att >> 6) & 1)) * 300 + c);
        float m;
        m = hv.x + t0.x + t1.x + t2.x; s.x += (m > 0.f ? m : 0.f);
        m = hv.y + t0.y + t1.y + t2.y; s.y += (m > 0.f ? m : 0.f);
        m = hv.z + t0.z + t1.z + t2.z; s.z += (m > 0.f ? m : 0.f);
        m = hv.w + t0.w + t1.w + t2.w; s.w += (m > 0.f ? m : 0.f);
    }
    *(float4*)(agg + (long)n * 300 + c) = s;
}

// ---------------- GEMM1 fused: z1 = [(1+eps)h + agg] @ W1 + b1 ----------------
__global__ __launch_bounds__(256, 2)
void gemm1_fused(const float* __restrict__ h, const float* __restrict__ agg,
                 const float* __restrict__ eps, int l,
                 const unsigned short* __restrict__ Whi, const unsigned short* __restrict__ Wlo,
                 const float* __restrict__ bias, unsigned short* __restrict__ z1b,
                 float* __restrict__ stat_sum, float* __restrict__ stat_sq) {
    __shared__ unsigned short Ah[128 * 32], Al[128 * 32];
    __shared__ unsigned short Bh[128 * 32], Bl[128 * 32];
    __shared__ float ssum[128], ssq[128];

    const int tid  = threadIdx.x;
    const int wave = tid >> 6;
    const int lane = tid & 63;
    const long row0 = (long)blockIdx.y * 128;
    const long col0 = (long)blockIdx.x * 128;

    floatx4 acc[4][4];
#pragma unroll
    for (int mi = 0; mi < 4; mi++)
#pragma unroll
        for (int ni = 0; ni < 4; ni++)
            acc[mi][ni] = (floatx4){0.f, 0.f, 0.f, 0.f};

    const int sr  = lane >> 2;
    const int scb = (lane & 3) * 8;
    const int wm  = (wave >> 1) * 64;
    const int wn  = (wave & 1) * 64;
    const int fr  = lane & 15;
    const int q   = lane >> 4;
    const int arow = tid >> 1;            // A staging: 2 threads/row, 16 cols each
    const int acb  = (tid & 1) * 16;
    const long grow = row0 + arow;
    const bool rok  = grow < NN;
    const float ep = 1.f + eps[l];

    for (int k0 = 0; k0 < K1; k0 += 32) {
#pragma unroll
        for (int i = 0; i < 2; i++) {
            int r = wave * 32 + i * 16;
            const unsigned short* gbh = Whi + (col0 + r + sr) * (long)K1 + k0 + scb;
            const unsigned short* gbl = Wlo + (col0 + r + sr) * (long)K1 + k0 + scb;
            __builtin_amdgcn_global_load_lds((const __attribute__((address_space(1))) void*)gbh,
                                             (__attribute__((address_space(3))) void*)(Bh + r * 32), 16, 0, 0);
            __builtin_amdgcn_global_load_lds((const __attribute__((address_space(1))) void*)gbl,
                                             (__attribute__((address_space(3))) void*)(Bl + r * 32), 16, 0, 0);
        }
#pragma unroll
        for (int j = 0; j < 4; j++) {
            int cc = k0 + acb + j * 4;
            float4 hv, av;
            if (rok && cc < 300) {
                hv = *(const float4*)(h   + grow * 300 + cc);
                av = *(const float4*)(agg + grow * 300 + cc);
            } else {
                hv = make_float4(0.f, 0.f, 0.f, 0.f);
                av = hv;
            }
            ushort4 hi4, lo4;
            splitbf(ep * hv.x + av.x, hi4.x, lo4.x);
            splitbf(ep * hv.y + av.y, hi4.y, lo4.y);
            splitbf(ep * hv.z + av.z, hi4.z, lo4.z);
            splitbf(ep * hv.w + av.w, hi4.w, lo4.w);
            *(ushort4*)(Ah + arow * 32 + acb + j * 4) = hi4;
            *(ushort4*)(Al + arow * 32 + acb + j * 4) = lo4;
        }
        __syncthreads();
        short8 ah[4], alo[4], bh[4], blo[4];
#pragma unroll
        for (int mi = 0; mi < 4; mi++) {
            ah[mi]  = *(const short8*)(Ah + (wm + mi * 16 + fr) * 32 + q * 8);
            alo[mi] = *(const short8*)(Al + (wm + mi * 16 + fr) * 32 + q * 8);
        }
#pragma unroll
        for (int ni = 0; ni < 4; ni++) {
            bh[ni]  = *(const short8*)(Bh + (wn + ni * 16 + fr) * 32 + q * 8);
            blo[ni] = *(const short8*)(Bl + (wn + ni * 16 + fr) * 32 + q * 8);
        }
#pragma unroll
        for (int mi = 0; mi < 4; mi++)
#pragma unroll
            for (int ni = 0; ni < 4; ni++) {
                acc[mi][ni] = __builtin_amdgcn_mfma_f32_16x16x32_bf16(ah[mi],  bh[ni],  acc[mi][ni], 0, 0, 0);
                acc[mi][ni] = __builtin_amdgcn_mfma_f32_16x16x32_bf16(alo[mi], bh[ni],  acc[mi][ni], 0, 0, 0);
                acc[mi][ni] = __builtin_amdgcn_mfma_f32_16x16x32_bf16(ah[mi],  blo[ni], acc[mi][ni], 0, 0, 0);
            }
        __syncthreads();
    }

    if (tid < 128) { ssum[tid] = 0.f; ssq[tid] = 0.f; }
    __syncthreads();
#pragma unroll
    for (int ni = 0; ni < 4; ni++) {
        int cl = wn + ni * 16 + fr;
        long cg = col0 + cl;
        float bs = bias[cg];
        float psum = 0.f, psq = 0.f;
#pragma unroll
        for (int mi = 0; mi < 4; mi++) {
#pragma unroll
            for (int r = 0; r < 4; r++) {
                long rg = row0 + wm + mi * 16 + q * 4 + r;
                float v = acc[mi][ni][r] + bs;
                z1b[rg * N1 + cg] = f2bf(v);
                if (rg < NN) { psum += v; psq += v * v; }
            }
        }
        atomicAdd(&ssum[cl], psum);
        atomicAdd(&ssq[cl], psq);
    }
    __syncthreads();
    if (tid < 128) {
        atomicAdd(&stat_sum[col0 + tid], ssum[tid]);
        atomicAdd(&stat_sq[col0 + tid], ssq[tid]);
    }
}

// ---------------- GEMM2 fused: z2 = relu(BN(z1)) @ W2 + b2 ----------------
__global__ __launch_bounds__(256, 2)
void gemm2_fused(const unsigned short* __restrict__ z1b,
                 const float* __restrict__ scale, const float* __restrict__ shift,
                 const unsigned short* __restrict__ Whi, const unsigned short* __restrict__ Wlo,
                 const float* __restrict__ bias, float* __restrict__ z2f,
                 float* __restrict__ stat_sum, float* __restrict__ stat_sq) {
    __shared__ unsigned short Ah[128 * 32], Al[128 * 32];
    __shared__ unsigned short Bh[128 * 32], Bl[128 * 32];
    __shared__ float sSc[K2], sSh[K2];
    __shared__ float ssum[128], ssq[128];

    const int tid  = threadIdx.x;
    const int wave = tid >> 6;
    const int lane = tid & 63;
    const long row0 = (long)blockIdx.y * 128;
    const long col0 = (long)blockIdx.x * 128;

    for (int i = tid; i < K2; i += 256) { sSc[i] = scale[i]; sSh[i] = shift[i]; }

    floatx4 acc[4][4];
#pragma unroll
    for (int mi = 0; mi < 4; mi++)
#pragma unroll
        for (int ni = 0; ni < 4; ni++)
            acc[mi][ni] = (floatx4){0.f, 0.f, 0.f, 0.f};

    const int sr  = lane >> 2;
    const int scb = (lane & 3) * 8;
    const int wm  = (wave >> 1) * 64;
    const int wn  = (wave & 1) * 64;
    const int fr  = lane & 15;
    const int q   = lane >> 4;
    const int arow = tid >> 1;
    const int acb  = (tid & 1) * 16;
    const long grow = row0 + arow;
    const bool rok  = grow < NN;
    __syncthreads();     // sSc/sSh visible

    for (int k0 = 0; k0 < K2; k0 += 32) {
#pragma unroll
        for (int i = 0; i < 2; i++) {
            int r = wave * 32 + i * 16;
            const unsigned short* gbh = Whi + (col0 + r + sr) * (long)K2 + k0 + scb;
            const unsigned short* gbl = Wlo + (col0 + r + sr) * (long)K2 + k0 + scb;
            __builtin_amdgcn_global_load_lds((const __attribute__((address_space(1))) void*)gbh,
                                             (__attribute__((address_space(3))) void*)(Bh + r * 32), 16, 0, 0);
            __builtin_amdgcn_global_load_lds((const __attribute__((address_space(1))) void*)gbl,
                                             (__attribute__((address_space(3))) void*)(Bl + r * 32), 16, 0, 0);
        }
#pragma unroll
        for (int j = 0; j < 4; j++) {
            int cc = k0 + acb + j * 4;
            ushort4 xv;
            if (rok) xv = *(const ushort4*)(z1b + grow * K2 + cc);
            else     { xv.x = 0; xv.y = 0; xv.z = 0; xv.w = 0; }
            const float4 sc = *(const float4*)(sSc + cc);
            const float4 sh = *(const float4*)(sSh + cc);
            ushort4 hi4, lo4;
            splitbf(fmaxf(bf2f(xv.x) * sc.x + sh.x, 0.f), hi4.x, lo4.x);
            splitbf(fmaxf(bf2f(xv.y) * sc.y + sh.y, 0.f), hi4.y, lo4.y);
            splitbf(fmaxf(bf2f(xv.z) * sc.z + sh.z, 0.f), hi4.z, lo4.z);
            splitbf(fmaxf(bf2f(xv.w) * sc.w + sh.w, 0.f), hi4.w, lo4.w);
            *(ushort4*)(Ah + arow * 32 + acb + j * 4) = hi4;
            *(ushort4*)(Al + arow * 32 + acb + j * 4) = lo4;
        }
        __syncthreads();
        short8 ah[4], alo[4], bh[4], blo[4];
#pragma unroll
        for (int mi = 0; mi < 4; mi++) {
            ah[mi]  = *(const short8*)(Ah + (wm + mi * 16 + fr) * 32 + q * 8);
            alo[mi] = *(const short8*)(Al + (wm + mi * 16 + fr) * 32 + q * 8);
        }
#pragma unroll
        for (int ni = 0; ni < 4; ni++) {
            bh[ni]  = *(const short8*)(Bh + (wn + ni * 16 + fr) * 32 + q * 8);
            blo[ni] = *(const short8*)(Bl + (wn + ni * 16 + fr) * 32 + q * 8);
        }
#pragma unroll
        for (int mi = 0; mi < 4; mi++)
#pragma unroll
            for (int ni = 0; ni < 4; ni++) {
                acc[mi][ni] = __builtin_amdgcn_mfma_f32_16x16x32_bf16(ah[mi],  bh[ni],  acc[mi][ni], 0, 0, 0);
                acc[mi][ni] = __builtin_amdgcn_mfma_f32_16x16x32_bf16(alo[mi], bh[ni],  acc[mi][ni], 0, 0, 0);
                acc[mi][ni] = __builtin_amdgcn_mfma_f32_16x16x32_bf16(ah[mi],  blo[ni], acc[mi][ni], 0, 0, 0);
            }
        __syncthreads();
    }

    if (tid < 128) { ssum[tid] = 0.f; ssq[tid] = 0.f; }
    __syncthreads();
#pragma unroll
    for (int ni = 0; ni < 4; ni++) {
        int cl = wn + ni * 16 + fr;
        long cg = col0 + cl;
        float bs = bias[cg];
        float psum = 0.f, psq = 0.f;
#pragma unroll
        for (int mi = 0; mi < 4; mi++) {
#pragma unroll
            for (int r = 0; r < 4; r++) {
                long rg = row0 + wm + mi * 16 + q * 4 + r;
                float v = acc[mi][ni][r] + bs;
                if (cg < 300) z2f[rg * 300 + cg] = v;
                if (rg < NN) { psum += v; psq += v * v; }
            }
        }
        atomicAdd(&ssum[cl], psum);
        atomicAdd(&ssq[cl], psq);
    }
    __syncthreads();
    if (tid < 128) {
        atomicAdd(&stat_sum[col0 + tid], ssum[tid]);
        atomicAdd(&stat_sq[col0 + tid], ssq[tid]);
    }
}

// ---------------- BN finalize ----------------
__global__ void bn_finalize(const float* __restrict__ sum, const float* __restrict__ sq,
                            const float* __restrict__ g, const float* __restrict__ be,
                            float* __restrict__ scale, float* __restrict__ shift, int n) {
    int c = blockIdx.x * blockDim.x + threadIdx.x;
    if (c >= n) return;
    const float invN = 1.f / (float)NN;
    float mu  = sum[c] * invN;
    float var = sq[c] * invN - mu * mu;
    float rs  = rsqrtf(var + BN_EPS);
    float s   = rs * g[c];               // pad cols: g=0 -> s=0
    scale[c] = s;
    shift[c] = be[c] - mu * s;
}

// ---------------- final BN (+ReLU except last layer) -> f32 h ----------------
__global__ void bn2_out(const float* __restrict__ z2,
                        const float* __restrict__ scale, const float* __restrict__ shift,
                        float* __restrict__ out, int do_relu) {
    int idx = blockIdx.x * blockDim.x + threadIdx.x;
    if (idx >= NN * 75) return;
    int n = idx / 75;
    int c = (idx % 75) * 4;
    const float4 v  = *(const float4*)(z2 + (long)n * 300 + c);
    const float4 sc = *(const float4*)(scale + c);
    const float4 sh = *(const float4*)(shift + c);
    float4 o;
    o.x = v.x * sc.x + sh.x;
    o.y = v.y * sc.y + sh.y;
    o.z = v.z * sc.z + sh.z;
    o.w = v.w * sc.w + sh.w;
    if (do_relu) {
        o.x = fmaxf(o.x, 0.f); o.y = fmaxf(o.y, 0.f);
        o.z = fmaxf(o.z, 0.f); o.w = fmaxf(o.w, 0.f);
    }
    *(float4*)(out + (long)n * 300 + c) = o;
}

extern "C" void kernel_launch(void* const* d_in, const int* in_sizes, int n_in,
                              void* d_out, int out_size, void* d_ws, size_t ws_size,
                              hipStream_t stream) {
    const int*   xf   = (const int*)d_in[0];
    const int*   ei   = (const int*)d_in[1];
    const int*   ea   = (const int*)d_in[2];
    const float* atab = (const float*)d_in[3];
    const float* btab = (const float*)d_in[4];
    const float* eps  = (const float*)d_in[5];
    const float* W1   = (const float*)d_in[6];
    const float* b1   = (const float*)d_in[7];
    const float* g1   = (const float*)d_in[8];
    const float* be1  = (const float*)d_in[9];
    const float* W2   = (const float*)d_in[10];
    const float* b2   = (const float*)d_in[11];
    const float* g2   = (const float*)d_in[12];
    const float* be2  = (const float*)d_in[13];
    float* hbuf = (float*)d_out;                 // h lives in d_out across layers

    char* ws = (char*)d_ws;
    size_t off = 0;
    auto alloc = [&](size_t bytes) { size_t o = off; off += (bytes + 255) & ~(size_t)255; return o; };
    // z1 bf16 [MPAD,640]  (128.1 MB)
    unsigned short* z1b = (unsigned short*)(ws + alloc((size_t)MPAD * N1 * 2));
    // shared region: agg f32 [NN,300] / z2 f32 [MPAD,300]  (120.1 MB)
    char* regA = ws + alloc((size_t)MPAD * 300 * 4);
    float* agg = (float*)regA;
    float* z2f = (float*)regA;
    unsigned short* W1hi = (unsigned short*)(ws + alloc((size_t)NL * N1 * K1 * 2));
    unsigned short* W1lo = (unsigned short*)(ws + alloc((size_t)NL * N1 * K1 * 2));
    unsigned short* W2hi = (unsigned short*)(ws + alloc((size_t)NL * N2 * K2 * 2));
    unsigned short* W2lo = (unsigned short*)(ws + alloc((size_t)NL * N2 * K2 * 2));
    float* b1p  = (float*)(ws + alloc((size_t)NL * N1 * 4));
    float* g1p  = (float*)(ws + alloc((size_t)NL * N1 * 4));
    float* be1p = (float*)(ws + alloc((size_t)NL * N1 * 4));
    float* b2p  = (float*)(ws + alloc((size_t)NL * N2 * 4));
    float* g2p  = (float*)(ws + alloc((size_t)NL * N2 * 4));
    float* be2p = (float*)(ws + alloc((size_t)NL * N2 * 4));
    float* sums = (float*)(ws + alloc(2048 * 4));    // sum1[640] sq1[640] sum2[384] sq2[384]
    float* scale1 = (float*)(ws + alloc(N1 * 4));
    float* shift1 = (float*)(ws + alloc(N1 * 4));
    float* scale2 = (float*)(ws + alloc(N2 * 4));
    float* shift2 = (float*)(ws + alloc(N2 * 4));
    // CSR: deg/fillc/rowptr + src/att  (~2.8 MB)
    int* deg     = (int*)(ws + alloc((size_t)NN * 4));
    int* fillc   = (int*)(ws + alloc((size_t)NN * 4));
    int* rowptr  = (int*)(ws + alloc((size_t)(NN + 1) * 4));
    int* csr_src = (int*)(ws + alloc((size_t)NE * 4));
    int* csr_att = (int*)(ws + alloc((size_t)NE * 4));
    (void)ws_size; (void)in_sizes; (void)n_in; (void)out_size;
    // total ws: ~260 MB (R1's 318 MB ran clean; R2's 526 MB core-dumped)

    // ---- one-time prep ----
    prep_w1<<<(NL * N1 * K1 + 255) / 256, 256, 0, stream>>>(W1, W1hi, W1lo);
    prep_w2<<<(NL * N2 * K2 + 255) / 256, 256, 0, stream>>>(W2, W2hi, W2lo);
    prep_vec<<<(NL * N1 + 255) / 256, 256, 0, stream>>>(b1, g1, be1, b2, g2, be2,
                                                        b1p, g1p, be1p, b2p, g2p, be2p);
    atom_enc<<<(NN * 75 + 255) / 256, 256, 0, stream>>>(xf, atab, hbuf);
    // CSR build
    hipMemsetAsync(deg, 0, (size_t)NN * 4, stream);
    hipMemsetAsync(fillc, 0, (size_t)NN * 4, stream);
    count_deg<<<(NE + 255) / 256, 256, 0, stream>>>(ei, deg);
    scan_rowptr<<<1, 1024, 0, stream>>>(deg, rowptr);
    fill_csr<<<(NE + 255) / 256, 256, 0, stream>>>(ei, ea, rowptr, fillc, csr_src, csr_att);

    for (int l = 0; l < NL; l++) {
        hipMemsetAsync(sums, 0, 2048 * 4, stream);
        gather_agg<<<(NN * 75 + 255) / 256, 256, 0, stream>>>(
            hbuf, rowptr, csr_src, csr_att, btab + (size_t)l * 5400, agg);
        gemm1_fused<<<dim3(N1 / 128, MTILES), 256, 0, stream>>>(
            hbuf, agg, eps, l, W1hi + (size_t)l * N1 * K1, W1lo + (size_t)l * N1 * K1,
            b1p + l * N1, z1b, sums + 0, sums + 640);
        bn_finalize<<<(N1 + 255) / 256, 256, 0, stream>>>(sums + 0, sums + 640,
            g1p + l * N1, be1p + l * N1, scale1, shift1, N1);
        gemm2_fused<<<dim3(N2 / 128, MTILES), 256, 0, stream>>>(
            z1b, scale1, shift1, W2hi + (size_t)l * N2 * K2, W2lo + (size_t)l * N2 * K2,
            b2p + l * N2, z2f, sums + 1280, sums + 1664);
        bn_finalize<<<(N2 + 255) / 256, 256, 0, stream>>>(sums + 1280, sums + 1664,
            g2p + l * N2, be2p + l * N2, scale2, shift2, N2);
        bn2_out<<<(NN * 75 + 255) / 256, 256, 0, stream>>>(z2f, scale2, shift2, hbuf, (l < NL - 1) ? 1 : 0);
    }
}

// Round 5
// 2677.584 us; speedup vs baseline: 3.4788x; 2.1074x over previous
//
#include <hip/hip_runtime.h>

#define NL    5
#define NN    100000
#define NE    200000
#define MPAD  100096       // 782 * 128
#define MTILES 782
#define K1    320          // EMB 300 padded
#define N1    640          // 600 padded
#define K2    640
#define N2    384          // 300 padded
#define BN_EPS 1e-5f
#define G1    (MTILES * 5) // gemm1 grid (5 col-tiles)
#define G2    (MTILES * 3) // gemm2 grid (3 col-tiles)

typedef __attribute__((ext_vector_type(8))) short   short8;
typedef __attribute__((ext_vector_type(4))) float   floatx4;

// exact hi/lo bf16 split: x == bf(hi) + bf(lo) + O(2^-17 |x|)
__device__ inline void splitbf(float x, unsigned short& hi, unsigned short& lo) {
    unsigned u = __float_as_uint(x);
    unsigned hb = u & 0xFFFF0000u;
    float lf = x - __uint_as_float(hb);     // exact (shares leading bits)
    hi = (unsigned short)(u >> 16);
    lo = (unsigned short)(__float_as_uint(lf) >> 16);
}
__device__ inline unsigned short f2bf(float f) {
    unsigned u = __float_as_uint(f);
    unsigned r = u + 0x7FFFu + ((u >> 16) & 1u);   // RNE
    return (unsigned short)(r >> 16);
}
__device__ inline float bf2f(unsigned short b) {
    return __uint_as_float(((unsigned)b) << 16);
}

// XCD-contiguous swizzle: blocks with id%8==x (same XCD under round-robin
// dispatch) get a CONTIGUOUS run of (row, col) work items, col-fastest, so the
// col-tiles of one row-block share that XCD's L2 (per-XCD L2 not cross-coherent).
__device__ inline void swz(int id, int G, int NC, int& row, int& col) {
    int q = G >> 3, r = G & 7;
    int x = id & 7, k = id >> 3;
    int w = x * q + (x < r ? x : r) + k;
    row = w / NC; col = w % NC;
}

// ---------------- weight prep: hi/lo planes, n-major, padded ----------------
__global__ void prep_w1(const float* __restrict__ W1,
                        unsigned short* __restrict__ Whi, unsigned short* __restrict__ Wlo) {
    int idx = blockIdx.x * blockDim.x + threadIdx.x;
    if (idx >= NL * N1 * K1) return;                // [l][n<640][k<320]
    int l = idx / (N1 * K1);
    int rem = idx % (N1 * K1);
    int n = rem / K1;
    int k = rem % K1;
    float v = (k < 300 && n < 600) ? W1[((long)l * 300 + k) * 600 + n] : 0.f;
    unsigned short hi, lo; splitbf(v, hi, lo);
    Whi[idx] = hi; Wlo[idx] = lo;
}

__global__ void prep_w2(const float* __restrict__ W2,
                        unsigned short* __restrict__ Whi, unsigned short* __restrict__ Wlo) {
    int idx = blockIdx.x * blockDim.x + threadIdx.x;
    if (idx >= NL * N2 * K2) return;                // [l][d<384][k<640]
    int l = idx / (N2 * K2);
    int rem = idx % (N2 * K2);
    int d = rem / K2;
    int k = rem % K2;
    float v = (d < 300 && k < 600) ? W2[((long)l * 600 + k) * 300 + d] : 0.f;
    unsigned short hi, lo; splitbf(v, hi, lo);
    Whi[idx] = hi; Wlo[idx] = lo;
}

__global__ void prep_vec(const float* __restrict__ b1, const float* __restrict__ g1, const float* __restrict__ be1,
                         const float* __restrict__ b2, const float* __restrict__ g2, const float* __restrict__ be2,
                         float* __restrict__ b1p, float* __restrict__ g1p, float* __restrict__ be1p,
                         float* __restrict__ b2p, float* __restrict__ g2p, float* __restrict__ be2p) {
    int idx = blockIdx.x * blockDim.x + threadIdx.x;
    if (idx < NL * N1) {
        int l = idx / N1, n = idx % N1;
        bool ok = (n < 600);
        b1p[idx]  = ok ? b1[l * 600 + n]  : 0.f;
        g1p[idx]  = ok ? g1[l * 600 + n]  : 0.f;
        be1p[idx] = ok ? be1[l * 600 + n] : 0.f;
    }
    if (idx < NL * N2) {
        int l = idx / N2, d = idx % N2;
        bool ok = (d < 300);
        b2p[idx]  = ok ? b2[l * 300 + d]  : 0.f;
        g2p[idx]  = ok ? g2[l * 300 + d]  : 0.f;
        be2p[idx] = ok ? be2[l * 300 + d] : 0.f;
    }
}

// ---------------- atom encoder ----------------
__global__ void atom_enc(const int* __restrict__ xf, const float* __restrict__ tab,
                         float* __restrict__ h) {
    int idx = blockIdx.x * blockDim.x + threadIdx.x;
    if (idx >= NN * 75) return;
    int n = idx / 75;
    int c = (idx % 75) * 4;
    float4 s = make_float4(0.f, 0.f, 0.f, 0.f);
#pragma unroll
    for (int f = 0; f < 9; f++) {
        int v = xf[n * 9 + f];
        const float4 t = *(const float4*)(tab + (long)(f * 119 + v) * 300 + c);
        s.x += t.x; s.y += t.y; s.z += t.z; s.w += t.w;
    }
    *(float4*)(h + (long)n * 300 + c) = s;
}

// ---------------- CSR build (once per call; graph static across layers) ----------------
__global__ void count_deg(const int* __restrict__ ei, int* __restrict__ deg) {
    int e = blockIdx.x * blockDim.x + threadIdx.x;
    if (e >= NE) return;
    atomicAdd(&deg[ei[NE + e]], 1);
}

__global__ void scan_rowptr(const int* __restrict__ deg, int* __restrict__ rowptr) {
    __shared__ int stot[1024];
    const int tid = threadIdx.x;
    const int CH = (NN + 1023) / 1024;     // 98
    const int base = tid * CH;
    int s = 0;
    for (int i = 0; i < CH; i++) {
        int idx = base + i;
        if (idx < NN) s += deg[idx];
    }
    stot[tid] = s;
    __syncthreads();
    for (int offs = 1; offs < 1024; offs <<= 1) {
        int v = (tid >= offs) ? stot[tid - offs] : 0;
        __syncthreads();
        stot[tid] += v;
        __syncthreads();
    }
    int run = (tid == 0) ? 0 : stot[tid - 1];
    for (int i = 0; i < CH; i++) {
        int idx = base + i;
        if (idx <= NN) rowptr[idx] = run;
        if (idx < NN) run += deg[idx];
    }
}

__global__ void fill_csr(const int* __restrict__ ei, const int* __restrict__ ea,
                         const int* __restrict__ rowptr, int* __restrict__ fillc,
                         int* __restrict__ csr_src, int* __restrict__ csr_att) {
    int e = blockIdx.x * blockDim.x + threadIdx.x;
    if (e >= NE) return;
    int dst = ei[NE + e];
    int pos = atomicAdd(&fillc[dst], 1);
    int slot = rowptr[dst] + pos;
    csr_src[slot] = ei[e];
    csr_att[slot] = ea[e * 3] | (ea[e * 3 + 1] << 3) | (ea[e * 3 + 2] << 6);
}

// ---- gather + GIN combine + exact split, fused:
// zin[n] = split_bf16((1+eps)h[n] + sum_{e in(n)} relu(h[src]+bond))
// layout: [MPAD][640] bf16, cols 0..319 = hi plane, 320..639 = lo plane.
__global__ void gather_zin(const float* __restrict__ h,
                           const int* __restrict__ rowptr,
                           const int* __restrict__ csr_src, const int* __restrict__ csr_att,
                           const float* __restrict__ bond,
                           const float* __restrict__ eps, int l,
                           unsigned short* __restrict__ zin) {
    int idx = blockIdx.x * blockDim.x + threadIdx.x;
    if (idx >= NN * 80) return;
    int n = idx / 80;
    int c = (idx % 80) * 4;
    ushort4 hi4, lo4;
    if (c < 300) {
        int p0 = rowptr[n], p1 = rowptr[n + 1];
        float4 s = make_float4(0.f, 0.f, 0.f, 0.f);
        for (int j = p0; j < p1; j++) {
            int src = csr_src[j];
            int att = csr_att[j];
            const float4 hv = *(const float4*)(h + (long)src * 300 + c);
            const float4 t0 = *(const float4*)(bond + (0 * 6 + (att & 7)) * 300 + c);
            const float4 t1 = *(const float4*)(bond + (1 * 6 + ((att >> 3) & 7)) * 300 + c);
            const float4 t2 = *(const float4*)(bond + (2 * 6 + ((att >> 6) & 1)) * 300 + c);
            float m;
            m = hv.x + t0.x + t1.x + t2.x; s.x += (m > 0.f ? m : 0.f);
            m = hv.y + t0.y + t1.y + t2.y; s.y += (m > 0.f ? m : 0.f);
            m = hv.z + t0.z + t1.z + t2.z; s.z += (m > 0.f ? m : 0.f);
            m = hv.w + t0.w + t1.w + t2.w; s.w += (m > 0.f ? m : 0.f);
        }
        const float ep = 1.f + eps[l];
        const float4 hn = *(const float4*)(h + (long)n * 300 + c);
        splitbf(ep * hn.x + s.x, hi4.x, lo4.x);
        splitbf(ep * hn.y + s.y, hi4.y, lo4.y);
        splitbf(ep * hn.z + s.z, hi4.z, lo4.z);
        splitbf(ep * hn.w + s.w, hi4.w, lo4.w);
    } else {
        hi4.x = hi4.y = hi4.z = hi4.w = 0;
        lo4.x = lo4.y = lo4.z = lo4.w = 0;
    }
    *(ushort4*)(zin + (long)n * 640 + c)       = hi4;
    *(ushort4*)(zin + (long)n * 640 + 320 + c) = lo4;
}

// ---------------- GEMM1: z1 = zin @ W1 + b1 (split-exact, pre-split A) ----------------
__global__ __launch_bounds__(256, 2)
void gemm1_pre(const unsigned short* __restrict__ zin,
               const unsigned short* __restrict__ Whi, const unsigned short* __restrict__ Wlo,
               const float* __restrict__ bias, unsigned short* __restrict__ z1b,
               float* __restrict__ stat_sum, float* __restrict__ stat_sq) {
    __shared__ unsigned short Ah[128 * 32], Al[128 * 32];
    __shared__ unsigned short Bh[128 * 32], Bl[128 * 32];
    __shared__ float ssum[128], ssq[128];

    const int tid  = threadIdx.x;
    const int wave = tid >> 6;
    const int lane = tid & 63;
    int rowb, colb; swz(blockIdx.x, G1, 5, rowb, colb);
    const long row0 = (long)rowb * 128;
    const long col0 = (long)colb * 128;

    floatx4 acc[4][4];
#pragma unroll
    for (int mi = 0; mi < 4; mi++)
#pragma unroll
        for (int ni = 0; ni < 4; ni++)
            acc[mi][ni] = (floatx4){0.f, 0.f, 0.f, 0.f};

    const int sr  = lane >> 2;
    const int scb = (lane & 3) * 8;
    const int wm  = (wave >> 1) * 64;
    const int wn  = (wave & 1) * 64;
    const int fr  = lane & 15;
    const int q   = lane >> 4;

    for (int k0 = 0; k0 < K1; k0 += 32) {
#pragma unroll
        for (int i = 0; i < 2; i++) {
            int r = wave * 32 + i * 16;
            const unsigned short* gah = zin + (row0 + r + sr) * 640 + k0 + scb;
            const unsigned short* gbh = Whi + (col0 + r + sr) * (long)K1 + k0 + scb;
            const unsigned short* gbl = Wlo + (col0 + r + sr) * (long)K1 + k0 + scb;
            __builtin_amdgcn_global_load_lds((const __attribute__((address_space(1))) void*)gah,
                                             (__attribute__((address_space(3))) void*)(Ah + r * 32), 16, 0, 0);
            __builtin_amdgcn_global_load_lds((const __attribute__((address_space(1))) void*)(gah + 320),
                                             (__attribute__((address_space(3))) void*)(Al + r * 32), 16, 0, 0);
            __builtin_amdgcn_global_load_lds((const __attribute__((address_space(1))) void*)gbh,
                                             (__attribute__((address_space(3))) void*)(Bh + r * 32), 16, 0, 0);
            __builtin_amdgcn_global_load_lds((const __attribute__((address_space(1))) void*)gbl,
                                             (__attribute__((address_space(3))) void*)(Bl + r * 32), 16, 0, 0);
        }
        __syncthreads();
        short8 ah[4], alo[4], bh[4], blo[4];
#pragma unroll
        for (int mi = 0; mi < 4; mi++) {
            ah[mi]  = *(const short8*)(Ah + (wm + mi * 16 + fr) * 32 + q * 8);
            alo[mi] = *(const short8*)(Al + (wm + mi * 16 + fr) * 32 + q * 8);
        }
#pragma unroll
        for (int ni = 0; ni < 4; ni++) {
            bh[ni]  = *(const short8*)(Bh + (wn + ni * 16 + fr) * 32 + q * 8);
            blo[ni] = *(const short8*)(Bl + (wn + ni * 16 + fr) * 32 + q * 8);
        }
#pragma unroll
        for (int mi = 0; mi < 4; mi++)
#pragma unroll
            for (int ni = 0; ni < 4; ni++) {
                acc[mi][ni] = __builtin_amdgcn_mfma_f32_16x16x32_bf16(ah[mi],  bh[ni],  acc[mi][ni], 0, 0, 0);
                acc[mi][ni] = __builtin_amdgcn_mfma_f32_16x16x32_bf16(alo[mi], bh[ni],  acc[mi][ni], 0, 0, 0);
                acc[mi][ni] = __builtin_amdgcn_mfma_f32_16x16x32_bf16(ah[mi],  blo[ni], acc[mi][ni], 0, 0, 0);
            }
        __syncthreads();
    }

    if (tid < 128) { ssum[tid] = 0.f; ssq[tid] = 0.f; }
    __syncthreads();
#pragma unroll
    for (int ni = 0; ni < 4; ni++) {
        int cl = wn + ni * 16 + fr;
        long cg = col0 + cl;
        float bs = bias[cg];
        float psum = 0.f, psq = 0.f;
#pragma unroll
        for (int mi = 0; mi < 4; mi++) {
#pragma unroll
            for (int r = 0; r < 4; r++) {
                long rg = row0 + wm + mi * 16 + q * 4 + r;
                float v = acc[mi][ni][r] + bs;
                z1b[rg * N1 + cg] = f2bf(v);
                if (rg < NN) { psum += v; psq += v * v; }
            }
        }
        atomicAdd(&ssum[cl], psum);
        atomicAdd(&ssq[cl], psq);
    }
    __syncthreads();
    if (tid < 128) {
        atomicAdd(&stat_sum[col0 + tid], ssum[tid]);
        atomicAdd(&stat_sq[col0 + tid], ssq[tid]);
    }
}

// ---------------- GEMM2 fused: z2 = relu(BN(z1)) @ W2 + b2 ----------------
__global__ __launch_bounds__(256, 2)
void gemm2_fused(const unsigned short* __restrict__ z1b,
                 const float* __restrict__ scale, const float* __restrict__ shift,
                 const unsigned short* __restrict__ Whi, const unsigned short* __restrict__ Wlo,
                 const float* __restrict__ bias, float* __restrict__ z2f,
                 float* __restrict__ stat_sum, float* __restrict__ stat_sq) {
    __shared__ unsigned short Ah[128 * 32], Al[128 * 32];
    __shared__ unsigned short Bh[128 * 32], Bl[128 * 32];
    __shared__ float sSc[K2], sSh[K2];
    __shared__ float ssum[128], ssq[128];

    const int tid  = threadIdx.x;
    const int wave = tid >> 6;
    const int lane = tid & 63;
    int rowb, colb; swz(blockIdx.x, G2, 3, rowb, colb);
    const long row0 = (long)rowb * 128;
    const long col0 = (long)colb * 128;

    for (int i = tid; i < K2; i += 256) { sSc[i] = scale[i]; sSh[i] = shift[i]; }

    floatx4 acc[4][4];
#pragma unroll
    for (int mi = 0; mi < 4; mi++)
#pragma unroll
        for (int ni = 0; ni < 4; ni++)
            acc[mi][ni] = (floatx4){0.f, 0.f, 0.f, 0.f};

    const int sr  = lane >> 2;
    const int scb = (lane & 3) * 8;
    const int wm  = (wave >> 1) * 64;
    const int wn  = (wave & 1) * 64;
    const int fr  = lane & 15;
    const int q   = lane >> 4;
    const int arow = tid >> 1;
    const int acb  = (tid & 1) * 16;
    const long grow = row0 + arow;
    __syncthreads();     // sSc/sSh visible

    for (int k0 = 0; k0 < K2; k0 += 32) {
#pragma unroll
        for (int i = 0; i < 2; i++) {
            int r = wave * 32 + i * 16;
            const unsigned short* gbh = Whi + (col0 + r + sr) * (long)K2 + k0 + scb;
            const unsigned short* gbl = Wlo + (col0 + r + sr) * (long)K2 + k0 + scb;
            __builtin_amdgcn_global_load_lds((const __attribute__((address_space(1))) void*)gbh,
                                             (__attribute__((address_space(3))) void*)(Bh + r * 32), 16, 0, 0);
            __builtin_amdgcn_global_load_lds((const __attribute__((address_space(1))) void*)gbl,
                                             (__attribute__((address_space(3))) void*)(Bl + r * 32), 16, 0, 0);
        }
#pragma unroll
        for (int j = 0; j < 4; j++) {
            int cc = k0 + acb + j * 4;
            ushort4 xv = *(const ushort4*)(z1b + grow * K2 + cc);
            const float4 sc = *(const float4*)(sSc + cc);
            const float4 sh = *(const float4*)(sSh + cc);
            ushort4 hi4, lo4;
            // fmaxf squashes any NaN from stale pad rows (rg>=NN) to 0
            splitbf(fmaxf(bf2f(xv.x) * sc.x + sh.x, 0.f), hi4.x, lo4.x);
            splitbf(fmaxf(bf2f(xv.y) * sc.y + sh.y, 0.f), hi4.y, lo4.y);
            splitbf(fmaxf(bf2f(xv.z) * sc.z + sh.z, 0.f), hi4.z, lo4.z);
            splitbf(fmaxf(bf2f(xv.w) * sc.w + sh.w, 0.f), hi4.w, lo4.w);
            *(ushort4*)(Ah + arow * 32 + acb + j * 4) = hi4;
            *(ushort4*)(Al + arow * 32 + acb + j * 4) = lo4;
        }
        __syncthreads();
        short8 ah[4], alo[4], bh[4], blo[4];
#pragma unroll
        for (int mi = 0; mi < 4; mi++) {
            ah[mi]  = *(const short8*)(Ah + (wm + mi * 16 + fr) * 32 + q * 8);
            alo[mi] = *(const short8*)(Al + (wm + mi * 16 + fr) * 32 + q * 8);
        }
#pragma unroll
        for (int ni = 0; ni < 4; ni++) {
            bh[ni]  = *(const short8*)(Bh + (wn + ni * 16 + fr) * 32 + q * 8);
            blo[ni] = *(const short8*)(Bl + (wn + ni * 16 + fr) * 32 + q * 8);
        }
#pragma unroll
        for (int mi = 0; mi < 4; mi++)
#pragma unroll
            for (int ni = 0; ni < 4; ni++) {
                acc[mi][ni] = __builtin_amdgcn_mfma_f32_16x16x32_bf16(ah[mi],  bh[ni],  acc[mi][ni], 0, 0, 0);
                acc[mi][ni] = __builtin_amdgcn_mfma_f32_16x16x32_bf16(alo[mi], bh[ni],  acc[mi][ni], 0, 0, 0);
                acc[mi][ni] = __builtin_amdgcn_mfma_f32_16x16x32_bf16(ah[mi],  blo[ni], acc[mi][ni], 0, 0, 0);
            }
        __syncthreads();
    }

    if (tid < 128) { ssum[tid] = 0.f; ssq[tid] = 0.f; }
    __syncthreads();
#pragma unroll
    for (int ni = 0; ni < 4; ni++) {
        int cl = wn + ni * 16 + fr;
        long cg = col0 + cl;
        float bs = bias[cg];
        float psum = 0.f, psq = 0.f;
#pragma unroll
        for (int mi = 0; mi < 4; mi++) {
#pragma unroll
            for (int r = 0; r < 4; r++) {
                long rg = row0 + wm + mi * 16 + q * 4 + r;
                float v = acc[mi][ni][r] + bs;
                if (cg < 300) z2f[rg * 300 + cg] = v;
                if (rg < NN) { psum += v; psq += v * v; }
            }
        }
        atomicAdd(&ssum[cl], psum);
        atomicAdd(&ssq[cl], psq);
    }
    __syncthreads();
    if (tid < 128) {
        atomicAdd(&stat_sum[col0 + tid], ssum[tid]);
        atomicAdd(&stat_sq[col0 + tid], ssq[tid]);
    }
}

// ---------------- BN finalize ----------------
__global__ void bn_finalize(const float* __restrict__ sum, const float* __restrict__ sq,
                            const float* __restrict__ g, const float* __restrict__ be,
                            float* __restrict__ scale, float* __restrict__ shift, int n) {
    int c = blockIdx.x * blockDim.x + threadIdx.x;
    if (c >= n) return;
    const float invN = 1.f / (float)NN;
    float mu  = sum[c] * invN;
    float var = sq[c] * invN - mu * mu;
    float rs  = rsqrtf(var + BN_EPS);
    float s   = rs * g[c];               // pad cols: g=0 -> s=0
    scale[c] = s;
    shift[c] = be[c] - mu * s;
}

// ---------------- final BN (+ReLU except last layer) -> f32 h ----------------
__global__ void bn2_out(const float* __restrict__ z2,
                        const float* __restrict__ scale, const float* __restrict__ shift,
                        float* __restrict__ out, int do_relu) {
    int idx = blockIdx.x * blockDim.x + threadIdx.x;
    if (idx >= NN * 75) return;
    int n = idx / 75;
    int c = (idx % 75) * 4;
    const float4 v  = *(const float4*)(z2 + (long)n * 300 + c);
    const float4 sc = *(const float4*)(scale + c);
    const float4 sh = *(const float4*)(shift + c);
    float4 o;
    o.x = v.x * sc.x + sh.x;
    o.y = v.y * sc.y + sh.y;
    o.z = v.z * sc.z + sh.z;
    o.w = v.w * sc.w + sh.w;
    if (do_relu) {
        o.x = fmaxf(o.x, 0.f); o.y = fmaxf(o.y, 0.f);
        o.z = fmaxf(o.z, 0.f); o.w = fmaxf(o.w, 0.f);
    }
    *(float4*)(out + (long)n * 300 + c) = o;
}

extern "C" void kernel_launch(void* const* d_in, const int* in_sizes, int n_in,
                              void* d_out, int out_size, void* d_ws, size_t ws_size,
                              hipStream_t stream) {
    const int*   xf   = (const int*)d_in[0];
    const int*   ei   = (const int*)d_in[1];
    const int*   ea   = (const int*)d_in[2];
    const float* atab = (const float*)d_in[3];
    const float* btab = (const float*)d_in[4];
    const float* eps  = (const float*)d_in[5];
    const float* W1   = (const float*)d_in[6];
    const float* b1   = (const float*)d_in[7];
    const float* g1   = (const float*)d_in[8];
    const float* be1  = (const float*)d_in[9];
    const float* W2   = (const float*)d_in[10];
    const float* b2   = (const float*)d_in[11];
    const float* g2   = (const float*)d_in[12];
    const float* be2  = (const float*)d_in[13];
    float* hbuf = (float*)d_out;                 // h lives in d_out across layers

    char* ws = (char*)d_ws;
    size_t off = 0;
    auto alloc = [&](size_t bytes) { size_t o = off; off += (bytes + 255) & ~(size_t)255; return o; };
    // z1 bf16 [MPAD,640]  (128.1 MB)
    unsigned short* z1b = (unsigned short*)(ws + alloc((size_t)MPAD * N1 * 2));
    // time-shared region (128.1 MB): zin bf16 [MPAD,640] (hi|lo) -> z2f f32 [MPAD,300]
    char* regA = ws + alloc((size_t)MPAD * 640 * 2);
    unsigned short* zin = (unsigned short*)regA;
    float*          z2f = (float*)regA;
    unsigned short* W1hi = (unsigned short*)(ws + alloc((size_t)NL * N1 * K1 * 2));
    unsigned short* W1lo = (unsigned short*)(ws + alloc((size_t)NL * N1 * K1 * 2));
    unsigned short* W2hi = (unsigned short*)(ws + alloc((size_t)NL * N2 * K2 * 2));
    unsigned short* W2lo = (unsigned short*)(ws + alloc((size_t)NL * N2 * K2 * 2));
    float* b1p  = (float*)(ws + alloc((size_t)NL * N1 * 4));
    float* g1p  = (float*)(ws + alloc((size_t)NL * N1 * 4));
    float* be1p = (float*)(ws + alloc((size_t)NL * N1 * 4));
    float* b2p  = (float*)(ws + alloc((size_t)NL * N2 * 4));
    float* g2p  = (float*)(ws + alloc((size_t)NL * N2 * 4));
    float* be2p = (float*)(ws + alloc((size_t)NL * N2 * 4));
    float* sums = (float*)(ws + alloc(2048 * 4));    // sum1[640] sq1[640] sum2[384] sq2[384]
    float* scale1 = (float*)(ws + alloc(N1 * 4));
    float* shift1 = (float*)(ws + alloc(N1 * 4));
    float* scale2 = (float*)(ws + alloc(N2 * 4));
    float* shift2 = (float*)(ws + alloc(N2 * 4));
    // CSR: deg/fillc/rowptr + src/att  (~2.8 MB)
    int* deg     = (int*)(ws + alloc((size_t)NN * 4));
    int* fillc   = (int*)(ws + alloc((size_t)NN * 4));
    int* rowptr  = (int*)(ws + alloc((size_t)(NN + 1) * 4));
    int* csr_src = (int*)(ws + alloc((size_t)NE * 4));
    int* csr_att = (int*)(ws + alloc((size_t)NE * 4));
    (void)ws_size; (void)in_sizes; (void)n_in; (void)out_size;
    // total ws: ~266 MB (R1's 318 MB ran clean; R2's 526 MB core-dumped)

    // ---- one-time prep ----
    prep_w1<<<(NL * N1 * K1 + 255) / 256, 256, 0, stream>>>(W1, W1hi, W1lo);
    prep_w2<<<(NL * N2 * K2 + 255) / 256, 256, 0, stream>>>(W2, W2hi, W2lo);
    prep_vec<<<(NL * N1 + 255) / 256, 256, 0, stream>>>(b1, g1, be1, b2, g2, be2,
                                                        b1p, g1p, be1p, b2p, g2p, be2p);
    atom_enc<<<(NN * 75 + 255) / 256, 256, 0, stream>>>(xf, atab, hbuf);
    // CSR build
    hipMemsetAsync(deg, 0, (size_t)NN * 4, stream);
    hipMemsetAsync(fillc, 0, (size_t)NN * 4, stream);
    count_deg<<<(NE + 255) / 256, 256, 0, stream>>>(ei, deg);
    scan_rowptr<<<1, 1024, 0, stream>>>(deg, rowptr);
    fill_csr<<<(NE + 255) / 256, 256, 0, stream>>>(ei, ea, rowptr, fillc, csr_src, csr_att);

    for (int l = 0; l < NL; l++) {
        hipMemsetAsync(sums, 0, 2048 * 4, stream);
        gather_zin<<<(NN * 80 + 255) / 256, 256, 0, stream>>>(
            hbuf, rowptr, csr_src, csr_att, btab + (size_t)l * 5400, eps, l, zin);
        gemm1_pre<<<G1, 256, 0, stream>>>(
            zin, W1hi + (size_t)l * N1 * K1, W1lo + (size_t)l * N1 * K1,
            b1p + l * N1, z1b, sums + 0, sums + 640);
        bn_finalize<<<(N1 + 255) / 256, 256, 0, stream>>>(sums + 0, sums + 640,
            g1p + l * N1, be1p + l * N1, scale1, shift1, N1);
        gemm2_fused<<<G2, 256, 0, stream>>>(
            z1b, scale1, shift1, W2hi + (size_t)l * N2 * K2, W2lo + (size_t)l * N2 * K2,
            b2p + l * N2, z2f, sums + 1280, sums + 1664);
        bn_finalize<<<(N2 + 255) / 256, 256, 0, stream>>>(sums + 1280, sums + 1664,
            g2p + l * N2, be2p + l * N2, scale2, shift2, N2);
        bn2_out<<<(NN * 75 + 255) / 256, 256, 0, stream>>>(z2f, scale2, shift2, hbuf, (l < NL - 1) ? 1 : 0);
    }
}